// Round 1
// baseline (120.102 us; speedup 1.0000x reference)
//
#include <hip/hip_runtime.h>
#include <stdint.h>
#include <stddef.h>

typedef __bf16 bf16_t;
typedef __bf16 bf16x8 __attribute__((ext_vector_type(8)));
typedef __bf16 bf16x4 __attribute__((ext_vector_type(4)));
typedef float f32x4 __attribute__((ext_vector_type(4)));

__device__ __forceinline__ void gload_lds16(const void* g, void* l) {
  __builtin_amdgcn_global_load_lds(
      (const __attribute__((address_space(1))) uint32_t*)g,
      (__attribute__((address_space(3))) uint32_t*)l, 16, 0, 0);
}

// ---------------- prep kernels ----------------
// blocks 0..63:   w2s[r*256+m] = sum_n w2[((r*256+m)*64)+n]
// blocks 64..319: w3pt[(o*64+r)*256 + m] = bf16(w3[m*4096 + r*64 + o])
__global__ void prep1_k(const float* __restrict__ w2, const float* __restrict__ w3,
                        float* __restrict__ w2s, bf16_t* __restrict__ w3pt) {
  __shared__ float lds[64][65];
  const int b = blockIdx.x;
  const int t = threadIdx.x;
  if (b < 64) {
    const int r = b, m = t;
    const float4* p = (const float4*)(w2 + ((size_t)(r * 256 + m)) * 64);
    float s = 0.f;
#pragma unroll
    for (int i = 0; i < 16; ++i) {
      float4 v = p[i];
      s += (v.x + v.y) + (v.z + v.w);
    }
    w2s[r * 256 + m] = s;
    return;
  }
  const int b2 = b - 64;
  const int r = b2 & 63;
  const int mt = (b2 >> 6) * 64;
#pragma unroll
  for (int it = 0; it < 16; ++it) {
    int idx = t + it * 256;
    int ml = idx >> 6, o = idx & 63;
    lds[ml][o] = w3[(size_t)(mt + ml) * 4096 + r * 64 + o];
  }
  __syncthreads();
#pragma unroll
  for (int it = 0; it < 16; ++it) {
    int idx = t + it * 256;
    int o = idx >> 6, ml = idx & 63;
    w3pt[(size_t)(o * 64 + r) * 256 + mt + ml] = (bf16_t)lds[ml][o];
  }
}

// blocks 0..255: w1t[m*4096 + k] = bf16(w1[k*256+m] * w2s[(k&63)*256+m])  (LDS-tiled transpose)
// block 256:     c2[m] = sum_r bias1[r]*w2s[r*256+m] + 64*bias2[m]
__global__ void prep2_k(const float* __restrict__ w1, const float* __restrict__ w2s,
                        const float* __restrict__ bias1, const float* __restrict__ bias2,
                        bf16_t* __restrict__ w1t, float* __restrict__ c2) {
  __shared__ float lds[64][65];
  const int b = blockIdx.x;
  const int t = threadIdx.x;
  if (b == 256) {
    float s = 64.f * bias2[t];
#pragma unroll 8
    for (int r = 0; r < 64; ++r) s += bias1[r] * w2s[r * 256 + t];
    c2[t] = s;
    return;
  }
  const int k0 = (b >> 2) * 64;
  const int mt = (b & 3) * 64;
#pragma unroll
  for (int it = 0; it < 16; ++it) {
    int idx = t + it * 256;
    int kl = idx >> 6, ml = idx & 63;
    int k = k0 + kl;
    lds[kl][ml] = w1[(size_t)k * 256 + mt + ml] * w2s[(k & 63) * 256 + mt + ml];
  }
  __syncthreads();
#pragma unroll
  for (int it = 0; it < 16; ++it) {
    int idx = t + it * 256;
    int ml = idx >> 6, kl = idx & 63;
    w1t[(size_t)(mt + ml) * 4096 + k0 + kl] = (bf16_t)lds[kl][ml];
  }
}

// ---------------- GEMM1: S[t, kh*256+n] = sum_{k in half} bf16(X[t,k]) * W1T[n,k]  (+c2[n] on kh==0)
// grid 256 = 128 mtiles x 2 k-halves; 512 threads (8 waves, 2M x 4N); BM=64, BN=256, BK=64
__global__ __launch_bounds__(512, 1) void gemm1_k(
    const float* __restrict__ X, const bf16_t* __restrict__ W1T,
    const float* __restrict__ c2, bf16_t* __restrict__ S) {
  __shared__ __align__(16) bf16_t lA[2][64 * 64];
  __shared__ __align__(16) bf16_t lB[2][256 * 64];
  const int tid = threadIdx.x;
  const int lane = tid & 63;
  const int wv = tid >> 6;
  const int mtile = (int)blockIdx.x >> 1;
  const int kh = (int)blockIdx.x & 1;
  const size_t m0 = (size_t)mtile * 64;
  const int kbase = kh * 2048;
  const int wm = wv >> 2, wn = wv & 3;
  const int r0 = tid >> 4;  // 0..31
  const int f4 = tid & 15;

  f32x4 acc[2][4];
#pragma unroll
  for (int i = 0; i < 2; ++i)
#pragma unroll
    for (int j = 0; j < 4; ++j) acc[i][j] = (f32x4){0.f, 0.f, 0.f, 0.f};

  float4 aReg[2];

  auto issueA = [&](int kt) {
#pragma unroll
    for (int p = 0; p < 2; ++p) {
      int row = r0 + p * 32;
      aReg[p] = *(const float4*)(X + (m0 + row) * 4096 + (size_t)(kbase + kt * 64 + f4 * 4));
    }
  };
  auto writeA = [&](int buf) {
#pragma unroll
    for (int p = 0; p < 2; ++p) {
      int row = r0 + p * 32;
      int off = row * 128 + ((f4 * 8) ^ ((row & 7) << 4));
      bf16x4 v;
      v[0] = (bf16_t)aReg[p].x;
      v[1] = (bf16_t)aReg[p].y;
      v[2] = (bf16_t)aReg[p].z;
      v[3] = (bf16_t)aReg[p].w;
      *(bf16x4*)((char*)(&lA[buf][0]) + off) = v;
    }
  };
  auto issueB = [&](int buf, int kt) {
#pragma unroll
    for (int i = 0; i < 4; ++i) {
      int row = wv * 32 + i * 8 + (lane >> 3);
      int srckb = ((lane & 7) * 16) ^ ((row & 7) << 4);
      const char* src = (const char*)W1T + (size_t)row * 8192 + (size_t)(kbase + kt * 64) * 2 + srckb;
      char* dst = (char*)(&lB[buf][0]) + (wv * 32 + i * 8) * 128;  // wave-uniform base
      gload_lds16(src, dst);
    }
  };
  auto compute = [&](int buf) {
#pragma unroll
    for (int kk = 0; kk < 2; ++kk) {
      const int kb = kk * 64 + ((lane >> 4) * 16);
      bf16x8 af[2], bfr[4];
#pragma unroll
      for (int mf = 0; mf < 2; ++mf) {
        int row = wm * 32 + mf * 16 + (lane & 15);
        int off = row * 128 + (kb ^ ((row & 7) << 4));
        af[mf] = *(const bf16x8*)((const char*)(&lA[buf][0]) + off);
      }
#pragma unroll
      for (int nf = 0; nf < 4; ++nf) {
        int row = wn * 64 + nf * 16 + (lane & 15);
        int off = row * 128 + (kb ^ ((row & 7) << 4));
        bfr[nf] = *(const bf16x8*)((const char*)(&lB[buf][0]) + off);
      }
#pragma unroll
      for (int mf = 0; mf < 2; ++mf)
#pragma unroll
        for (int nf = 0; nf < 4; ++nf)
          acc[mf][nf] = __builtin_amdgcn_mfma_f32_16x16x32_bf16(af[mf], bfr[nf], acc[mf][nf], 0, 0, 0);
    }
  };

  issueA(0);
  issueB(0, 0);
  writeA(0);
  __syncthreads();
#pragma unroll 1
  for (int kt = 0; kt < 32; ++kt) {
    int cur = kt & 1;
    bool more = (kt + 1) < 32;
    if (more) {
      issueA(kt + 1);          // global fp32 loads to regs (latency hides under MFMA)
      issueB(cur ^ 1, kt + 1); // async direct-to-LDS
    }
    compute(cur);
    if (more) writeA(cur ^ 1); // cvt+ds_write after compute
    __syncthreads();
  }

#pragma unroll
  for (int nf = 0; nf < 4; ++nf) {
    int col = wn * 64 + nf * 16 + (lane & 15);
    float cadd = (kh == 0) ? c2[col] : 0.f;
#pragma unroll
    for (int mf = 0; mf < 2; ++mf) {
#pragma unroll
      for (int q = 0; q < 4; ++q) {
        int row = wm * 32 + mf * 16 + (lane >> 4) * 4 + q;
        S[(m0 + row) * 512 + (size_t)(kh * 256 + col)] = (bf16_t)(acc[mf][nf][q] + cadd);
      }
    }
  }
}

// ---------------- GEMM2: OUT[t, j] = sum_{c=0..511} S[t,c] * W3pT[j, c&255] + bias3[j&63]
// grid 2048 = 64 mtiles x 32 ntiles; 256 threads (4 waves, 2M x 2N); BM=128, BN=128, BK=64
__global__ __launch_bounds__(256, 1) void gemm2_k(
    const bf16_t* __restrict__ S, const bf16_t* __restrict__ W3pT,
    const float* __restrict__ bias3, float* __restrict__ OUT) {
  __shared__ __align__(16) bf16_t lA[2][128 * 64];
  __shared__ __align__(16) bf16_t lB[2][128 * 64];
  const int tid = threadIdx.x;
  const int lane = tid & 63;
  const int wv = tid >> 6;  // 0..3
  const int mt = (int)blockIdx.x >> 5;
  const int nt = (int)blockIdx.x & 31;
  const size_t m0 = (size_t)mt * 128;
  const int n0 = nt * 128;
  const int wm = wv >> 1, wn = wv & 1;

  f32x4 acc[4][4];
#pragma unroll
  for (int i = 0; i < 4; ++i)
#pragma unroll
    for (int j = 0; j < 4; ++j) acc[i][j] = (f32x4){0.f, 0.f, 0.f, 0.f};

  auto stage = [&](int buf, int kt) {
#pragma unroll
    for (int i = 0; i < 4; ++i) {
      int row = wv * 32 + i * 8 + (lane >> 3);
      int srckb = ((lane & 7) * 16) ^ ((row & 7) << 4);
      const char* srcA = (const char*)S + (m0 + row) * 1024 + (size_t)(kt * 128 + srckb);
      char* dstA = (char*)(&lA[buf][0]) + (wv * 32 + i * 8) * 128;
      gload_lds16(srcA, dstA);
      const char* srcB = (const char*)W3pT + (size_t)(n0 + row) * 512 + (size_t)((kt & 3) * 128 + srckb);
      char* dstB = (char*)(&lB[buf][0]) + (wv * 32 + i * 8) * 128;
      gload_lds16(srcB, dstB);
    }
  };
  auto compute = [&](int buf) {
#pragma unroll
    for (int kk = 0; kk < 2; ++kk) {
      const int kb = kk * 64 + ((lane >> 4) * 16);
      bf16x8 af[4], bfr[4];
#pragma unroll
      for (int mf = 0; mf < 4; ++mf) {
        int row = wm * 64 + mf * 16 + (lane & 15);
        int off = row * 128 + (kb ^ ((row & 7) << 4));
        af[mf] = *(const bf16x8*)((const char*)(&lA[buf][0]) + off);
      }
#pragma unroll
      for (int nf = 0; nf < 4; ++nf) {
        int row = wn * 64 + nf * 16 + (lane & 15);
        int off = row * 128 + (kb ^ ((row & 7) << 4));
        bfr[nf] = *(const bf16x8*)((const char*)(&lB[buf][0]) + off);
      }
#pragma unroll
      for (int mf = 0; mf < 4; ++mf)
#pragma unroll
        for (int nf = 0; nf < 4; ++nf)
          acc[mf][nf] = __builtin_amdgcn_mfma_f32_16x16x32_bf16(af[mf], bfr[nf], acc[mf][nf], 0, 0, 0);
    }
  };

  stage(0, 0);
  __syncthreads();
#pragma unroll 1
  for (int kt = 0; kt < 8; ++kt) {
    int cur = kt & 1;
    if (kt + 1 < 8) stage(cur ^ 1, kt + 1);
    compute(cur);
    __syncthreads();
  }

#pragma unroll
  for (int nf = 0; nf < 4; ++nf) {
    int jcol = wn * 64 + nf * 16 + (lane & 15);
    float b3 = bias3[jcol & 63];
    int j = n0 + jcol;
#pragma unroll
    for (int mf = 0; mf < 4; ++mf) {
#pragma unroll
      for (int q = 0; q < 4; ++q) {
        size_t row = m0 + (size_t)(wm * 64 + mf * 16 + (lane >> 4) * 4 + q);
        OUT[row * 4096 + j] = acc[mf][nf][q] + b3;
      }
    }
  }
}

extern "C" void kernel_launch(void* const* d_in, const int* in_sizes, int n_in,
                              void* d_out, int out_size, void* d_ws, size_t ws_size,
                              hipStream_t stream) {
  (void)in_sizes; (void)n_in; (void)out_size; (void)ws_size;
  const float* x  = (const float*)d_in[0];
  const float* w1 = (const float*)d_in[1];
  const float* w2 = (const float*)d_in[2];
  const float* w3 = (const float*)d_in[3];
  const float* b1 = (const float*)d_in[4];
  const float* b2 = (const float*)d_in[5];
  const float* b3 = (const float*)d_in[6];
  float* out = (float*)d_out;
  char* ws = (char*)d_ws;

  // workspace layout
  float*  w2s  = (float*)(ws + 0);                       // 64 KB
  float*  c2   = (float*)(ws + 65536);                   // 1 KB (+pad)
  bf16_t* w1t  = (bf16_t*)(ws + 69632);                  // 2 MB  [256][4096] bf16
  bf16_t* w3pt = (bf16_t*)(ws + 69632 + 2097152);        // 2 MB  [4096][256] bf16
  bf16_t* S    = (bf16_t*)(ws + 69632 + 2 * 2097152);    // 8 MB  [8192][512] bf16

  prep1_k<<<320, 256, 0, stream>>>(w2, w3, w2s, w3pt);
  prep2_k<<<257, 256, 0, stream>>>(w1, w2s, b1, b2, w1t, c2);
  gemm1_k<<<256, 512, 0, stream>>>(x, w1t, c2, S);
  gemm2_k<<<2048, 256, 0, stream>>>(S, w3pt, b3, out);
}

// Round 2
// 103.526 us; speedup vs baseline: 1.1601x; 1.1601x over previous
//
#include <hip/hip_runtime.h>
#include <stdint.h>
#include <stddef.h>

typedef __bf16 bf16_t;
typedef __bf16 bf16x8 __attribute__((ext_vector_type(8)));
typedef __bf16 bf16x4 __attribute__((ext_vector_type(4)));
typedef float f32x4 __attribute__((ext_vector_type(4)));

__device__ __forceinline__ void gload_lds16(const void* g, void* l) {
  __builtin_amdgcn_global_load_lds(
      (const __attribute__((address_space(1))) uint32_t*)g,
      (__attribute__((address_space(3))) uint32_t*)l, 16, 0, 0);
}

// ---------------- prep kernels ----------------
// blocks 0..63:   w2s[r*256+m] = sum_n w2[((r*256+m)*64)+n]
// blocks 64..319: w3pt[(o*64+r)*256 + m] = bf16(w3[m*4096 + r*64 + o])
__global__ void prep1_k(const float* __restrict__ w2, const float* __restrict__ w3,
                        float* __restrict__ w2s, bf16_t* __restrict__ w3pt) {
  __shared__ float lds[64][65];
  const int b = blockIdx.x;
  const int t = threadIdx.x;
  if (b < 64) {
    const int r = b, m = t;
    const float4* p = (const float4*)(w2 + ((size_t)(r * 256 + m)) * 64);
    float s = 0.f;
#pragma unroll
    for (int i = 0; i < 16; ++i) {
      float4 v = p[i];
      s += (v.x + v.y) + (v.z + v.w);
    }
    w2s[r * 256 + m] = s;
    return;
  }
  const int b2 = b - 64;
  const int r = b2 & 63;
  const int mt = (b2 >> 6) * 64;
#pragma unroll
  for (int it = 0; it < 16; ++it) {
    int idx = t + it * 256;
    int ml = idx >> 6, o = idx & 63;
    lds[ml][o] = w3[(size_t)(mt + ml) * 4096 + r * 64 + o];
  }
  __syncthreads();
#pragma unroll
  for (int it = 0; it < 16; ++it) {
    int idx = t + it * 256;
    int o = idx >> 6, ml = idx & 63;
    w3pt[(size_t)(o * 64 + r) * 256 + mt + ml] = (bf16_t)lds[ml][o];
  }
}

// blocks 0..255: w1t[m*4096 + k] = bf16(w1[k*256+m] * w2s[(k&63)*256+m])  (LDS-tiled transpose)
// block 256:     c2[m] = sum_r bias1[r]*w2s[r*256+m] + 64*bias2[m]
__global__ void prep2_k(const float* __restrict__ w1, const float* __restrict__ w2s,
                        const float* __restrict__ bias1, const float* __restrict__ bias2,
                        bf16_t* __restrict__ w1t, float* __restrict__ c2) {
  __shared__ float lds[64][65];
  const int b = blockIdx.x;
  const int t = threadIdx.x;
  if (b == 256) {
    float s = 64.f * bias2[t];
#pragma unroll 8
    for (int r = 0; r < 64; ++r) s += bias1[r] * w2s[r * 256 + t];
    c2[t] = s;
    return;
  }
  const int k0 = (b >> 2) * 64;
  const int mt = (b & 3) * 64;
#pragma unroll
  for (int it = 0; it < 16; ++it) {
    int idx = t + it * 256;
    int kl = idx >> 6, ml = idx & 63;
    int k = k0 + kl;
    lds[kl][ml] = w1[(size_t)k * 256 + mt + ml] * w2s[(k & 63) * 256 + mt + ml];
  }
  __syncthreads();
#pragma unroll
  for (int it = 0; it < 16; ++it) {
    int idx = t + it * 256;
    int ml = idx >> 6, kl = idx & 63;
    w1t[(size_t)(mt + ml) * 4096 + k0 + kl] = (bf16_t)lds[kl][ml];
  }
}

// ---------------- GEMM1: S4[t, kh*256+n] = sum_{k in quarter kh} bf16(X[t,k]) * W1T[n,k]
// grid 512 = 128 mtiles x 4 k-quarters; 512 threads (8 waves, 2M x 4N); BM=64, BN=256, BK=64
__global__ __launch_bounds__(512, 1) void gemm1_k(
    const float* __restrict__ X, const bf16_t* __restrict__ W1T,
    bf16_t* __restrict__ S4) {
  __shared__ __align__(16) bf16_t lA[2][64 * 64];
  __shared__ __align__(16) bf16_t lB[2][256 * 64];
  const int tid = threadIdx.x;
  const int lane = tid & 63;
  const int wv = tid >> 6;
  const int mtile = (int)blockIdx.x >> 2;
  const int kh = (int)blockIdx.x & 3;
  const size_t m0 = (size_t)mtile * 64;
  const int kbase = kh * 1024;
  const int wm = wv >> 2, wn = wv & 3;
  const int r0 = tid >> 4;  // 0..31
  const int f4 = tid & 15;

  f32x4 acc[2][4];
#pragma unroll
  for (int i = 0; i < 2; ++i)
#pragma unroll
    for (int j = 0; j < 4; ++j) acc[i][j] = (f32x4){0.f, 0.f, 0.f, 0.f};

  float4 aReg[2];

  auto issueA = [&](int kt) {
#pragma unroll
    for (int p = 0; p < 2; ++p) {
      int row = r0 + p * 32;
      aReg[p] = *(const float4*)(X + (m0 + row) * 4096 + (size_t)(kbase + kt * 64 + f4 * 4));
    }
  };
  auto writeA = [&](int buf) {
#pragma unroll
    for (int p = 0; p < 2; ++p) {
      int row = r0 + p * 32;
      int off = row * 128 + ((f4 * 8) ^ ((row & 7) << 4));
      bf16x4 v;
      v[0] = (bf16_t)aReg[p].x;
      v[1] = (bf16_t)aReg[p].y;
      v[2] = (bf16_t)aReg[p].z;
      v[3] = (bf16_t)aReg[p].w;
      *(bf16x4*)((char*)(&lA[buf][0]) + off) = v;
    }
  };
  auto issueB = [&](int buf, int kt) {
#pragma unroll
    for (int i = 0; i < 4; ++i) {
      int row = wv * 32 + i * 8 + (lane >> 3);
      int srckb = ((lane & 7) * 16) ^ ((row & 7) << 4);
      const char* src = (const char*)W1T + (size_t)row * 8192 + (size_t)(kbase + kt * 64) * 2 + srckb;
      char* dst = (char*)(&lB[buf][0]) + (wv * 32 + i * 8) * 128;  // wave-uniform base
      gload_lds16(src, dst);
    }
  };
  auto compute = [&](int buf) {
#pragma unroll
    for (int kk = 0; kk < 2; ++kk) {
      const int kb = kk * 64 + ((lane >> 4) * 16);
      bf16x8 af[2], bfr[4];
#pragma unroll
      for (int mf = 0; mf < 2; ++mf) {
        int row = wm * 32 + mf * 16 + (lane & 15);
        int off = row * 128 + (kb ^ ((row & 7) << 4));
        af[mf] = *(const bf16x8*)((const char*)(&lA[buf][0]) + off);
      }
#pragma unroll
      for (int nf = 0; nf < 4; ++nf) {
        int row = wn * 64 + nf * 16 + (lane & 15);
        int off = row * 128 + (kb ^ ((row & 7) << 4));
        bfr[nf] = *(const bf16x8*)((const char*)(&lB[buf][0]) + off);
      }
#pragma unroll
      for (int mf = 0; mf < 2; ++mf)
#pragma unroll
        for (int nf = 0; nf < 4; ++nf)
          acc[mf][nf] = __builtin_amdgcn_mfma_f32_16x16x32_bf16(af[mf], bfr[nf], acc[mf][nf], 0, 0, 0);
    }
  };

  issueA(0);
  issueB(0, 0);
  writeA(0);
  __syncthreads();
#pragma unroll 1
  for (int kt = 0; kt < 16; ++kt) {
    int cur = kt & 1;
    bool more = (kt + 1) < 16;
    if (more) {
      issueA(kt + 1);          // global fp32 loads to regs (latency hides under MFMA)
      issueB(cur ^ 1, kt + 1); // async direct-to-LDS
    }
    compute(cur);
    if (more) writeA(cur ^ 1); // cvt+ds_write after compute
    __syncthreads();
  }

#pragma unroll
  for (int nf = 0; nf < 4; ++nf) {
    int col = wn * 64 + nf * 16 + (lane & 15);
#pragma unroll
    for (int mf = 0; mf < 2; ++mf) {
#pragma unroll
      for (int q = 0; q < 4; ++q) {
        int row = wm * 32 + mf * 16 + (lane >> 4) * 4 + q;
        S4[(m0 + row) * 1024 + (size_t)(kh * 256 + col)] = (bf16_t)acc[mf][nf][q];
      }
    }
  }
}

// ---------------- reduce: S[t,m] = sum_h S4[t, h*256+m] + c2[m]
// grid 1024 x 256 threads; 8 bf16 per thread
__global__ void reduce_k(const bf16_t* __restrict__ S4, const float* __restrict__ c2,
                         bf16_t* __restrict__ S) {
  int gid = blockIdx.x * 256 + threadIdx.x;
  int row = gid >> 5;
  int c8 = (gid & 31) << 3;
  float s[8];
  float4 ca = *(const float4*)(c2 + c8);
  float4 cb = *(const float4*)(c2 + c8 + 4);
  s[0] = ca.x; s[1] = ca.y; s[2] = ca.z; s[3] = ca.w;
  s[4] = cb.x; s[5] = cb.y; s[6] = cb.z; s[7] = cb.w;
#pragma unroll
  for (int h = 0; h < 4; ++h) {
    bf16x8 v = *(const bf16x8*)(S4 + (size_t)row * 1024 + h * 256 + c8);
#pragma unroll
    for (int j = 0; j < 8; ++j) s[j] += (float)v[j];
  }
  bf16x8 o;
#pragma unroll
  for (int j = 0; j < 8; ++j) o[j] = (bf16_t)s[j];
  *(bf16x8*)(S + (size_t)row * 256 + c8) = o;
}

// ---------------- GEMM2: OUT[t, j] = sum_{m=0..255} S[t,m] * W3pT[j, m] + bias3[j&63]
// grid 2048 = 64 mtiles x 32 ntiles; 512 threads (8 waves, 2M x 4N); BM=128, BN=128, BK=64
__global__ __launch_bounds__(512, 1) void gemm2_k(
    const bf16_t* __restrict__ S, const bf16_t* __restrict__ W3pT,
    const float* __restrict__ bias3, float* __restrict__ OUT) {
  __shared__ __align__(16) bf16_t lA[2][128 * 64];
  __shared__ __align__(16) bf16_t lB[2][128 * 64];
  const int tid = threadIdx.x;
  const int lane = tid & 63;
  const int wv = tid >> 6;  // 0..7
  const int mt = (int)blockIdx.x >> 5;
  const int nt = (int)blockIdx.x & 31;
  const size_t m0 = (size_t)mt * 128;
  const int n0 = nt * 128;
  const int wm = wv >> 2, wn = wv & 3;  // 2M x 4N: wave owns 64 rows x 32 cols

  f32x4 acc[4][2];
#pragma unroll
  for (int i = 0; i < 4; ++i)
#pragma unroll
    for (int j = 0; j < 2; ++j) acc[i][j] = (f32x4){0.f, 0.f, 0.f, 0.f};

  auto stage = [&](int buf, int kt) {
#pragma unroll
    for (int p = 0; p < 2; ++p) {
      int row = wv * 8 + (lane >> 3) + p * 64;
      int srckb = ((lane & 7) * 16) ^ ((row & 7) << 4);
      const char* srcA = (const char*)S + (m0 + row) * 512 + (size_t)(kt * 128 + srckb);
      char* dstA = (char*)(&lA[buf][0]) + (wv * 8 + p * 64) * 128;
      gload_lds16(srcA, dstA);
      const char* srcB = (const char*)W3pT + (size_t)(n0 + row) * 512 + (size_t)(kt * 128 + srckb);
      char* dstB = (char*)(&lB[buf][0]) + (wv * 8 + p * 64) * 128;
      gload_lds16(srcB, dstB);
    }
  };
  auto compute = [&](int buf) {
#pragma unroll
    for (int kk = 0; kk < 2; ++kk) {
      const int kb = kk * 64 + ((lane >> 4) * 16);
      bf16x8 af[4], bfr[2];
#pragma unroll
      for (int mf = 0; mf < 4; ++mf) {
        int row = wm * 64 + mf * 16 + (lane & 15);
        int off = row * 128 + (kb ^ ((row & 7) << 4));
        af[mf] = *(const bf16x8*)((const char*)(&lA[buf][0]) + off);
      }
#pragma unroll
      for (int nf = 0; nf < 2; ++nf) {
        int row = wn * 32 + nf * 16 + (lane & 15);
        int off = row * 128 + (kb ^ ((row & 7) << 4));
        bfr[nf] = *(const bf16x8*)((const char*)(&lB[buf][0]) + off);
      }
#pragma unroll
      for (int mf = 0; mf < 4; ++mf)
#pragma unroll
        for (int nf = 0; nf < 2; ++nf)
          acc[mf][nf] = __builtin_amdgcn_mfma_f32_16x16x32_bf16(af[mf], bfr[nf], acc[mf][nf], 0, 0, 0);
    }
  };

  stage(0, 0);
  __syncthreads();
#pragma unroll 1
  for (int kt = 0; kt < 4; ++kt) {
    int cur = kt & 1;
    if (kt + 1 < 4) stage(cur ^ 1, kt + 1);
    compute(cur);
    __syncthreads();
  }

#pragma unroll
  for (int nf = 0; nf < 2; ++nf) {
    int jcol = wn * 32 + nf * 16 + (lane & 15);
    float b3 = bias3[jcol & 63];
    int j = n0 + jcol;
#pragma unroll
    for (int mf = 0; mf < 4; ++mf) {
#pragma unroll
      for (int q = 0; q < 4; ++q) {
        size_t row = m0 + (size_t)(wm * 64 + mf * 16 + (lane >> 4) * 4 + q);
        OUT[row * 4096 + j] = acc[mf][nf][q] + b3;
      }
    }
  }
}

extern "C" void kernel_launch(void* const* d_in, const int* in_sizes, int n_in,
                              void* d_out, int out_size, void* d_ws, size_t ws_size,
                              hipStream_t stream) {
  (void)in_sizes; (void)n_in; (void)out_size; (void)ws_size;
  const float* x  = (const float*)d_in[0];
  const float* w1 = (const float*)d_in[1];
  const float* w2 = (const float*)d_in[2];
  const float* w3 = (const float*)d_in[3];
  const float* b1 = (const float*)d_in[4];
  const float* b2 = (const float*)d_in[5];
  const float* b3 = (const float*)d_in[6];
  float* out = (float*)d_out;
  char* ws = (char*)d_ws;

  // workspace layout
  float*  w2s  = (float*)(ws + 0);                          // 64 KB
  float*  c2   = (float*)(ws + 65536);                      // 1 KB (+pad)
  bf16_t* w1t  = (bf16_t*)(ws + 69632);                     // 2 MB  [256][4096] bf16
  bf16_t* w3pt = (bf16_t*)(ws + 69632 + 2097152);           // 2 MB  [4096][256] bf16
  bf16_t* S4   = (bf16_t*)(ws + 69632 + 2 * 2097152);       // 16 MB [8192][1024] bf16
  bf16_t* S    = (bf16_t*)(ws + 69632 + 2 * 2097152 + 16777216);  // 4 MB [8192][256] bf16

  prep1_k<<<320, 256, 0, stream>>>(w2, w3, w2s, w3pt);
  prep2_k<<<257, 256, 0, stream>>>(w1, w2s, b1, b2, w1t, c2);
  gemm1_k<<<512, 512, 0, stream>>>(x, w1t, S4);
  reduce_k<<<1024, 256, 0, stream>>>(S4, c2, S);
  gemm2_k<<<2048, 512, 0, stream>>>(S, w3pt, b3, out);
}